// Round 1
// 125.818 us; speedup vs baseline: 1.0166x; 1.0166x over previous
//
#include <hip/hip_runtime.h>
#include <hip/hip_bf16.h>
#include <math.h>

#define T_SEQ 4096
#define C_DIM 128
#define B_SZ  4

typedef __attribute__((ext_vector_type(8))) short short8;
typedef __attribute__((ext_vector_type(4))) short short4v;
typedef __attribute__((ext_vector_type(4))) float f32x4;

__device__ __forceinline__ short f2bf(float f) {
    union { float fv; unsigned u; } v; v.fv = f;
    unsigned r = v.u + 0x7fff + ((v.u >> 16) & 1);
    return (short)(r >> 16);
}

__device__ __forceinline__ unsigned pk_bf16(float a, float b) {
    union { __hip_bfloat162 h2; unsigned u; } c;
    c.h2 = __float22bfloat162_rn(make_float2(a, b));
    return c.u;
}

__device__ __forceinline__ short8 load_f32x8_bf16(const float* p) {
    const float4* q = (const float4*)p;
    float4 a = q[0], b = q[1];
    short8 r;
    r[0] = f2bf(a.x); r[1] = f2bf(a.y); r[2] = f2bf(a.z); r[3] = f2bf(a.w);
    r[4] = f2bf(b.x); r[5] = f2bf(b.y); r[6] = f2bf(b.z); r[7] = f2bf(b.w);
    return r;
}

// 16B-per-lane async global->LDS DMA (wave-uniform LDS base + lane*16).
__device__ __forceinline__ void async_cp16(const short* g, short* l) {
    __builtin_amdgcn_global_load_lds(
        (const __attribute__((address_space(1))) unsigned int*)g,
        (__attribute__((address_space(3))) unsigned int*)l, 16, 0, 0);
}

// ---------------------------------------------------------------------------
// Kernel 1: QKV projection (unchanged). Q/K via transposed-C MFMA ->
// short4 stores; K/V in fragment-ordered layouts for flash's linear DMA.
// ---------------------------------------------------------------------------
__global__ __launch_bounds__(512) void qkv_proj(
    const float* __restrict__ x, const float* __restrict__ Wq,
    const float* __restrict__ Wk, const float* __restrict__ Wv,
    short* __restrict__ Q, short* __restrict__ Kf, short* __restrict__ Vf)
{
    __shared__ short8 Wl[2048];

    const int tid  = threadIdx.x;
    const int lane = tid & 63;
    const int ln15 = lane & 15;
    const int quad = lane >> 4;
    const int mat  = blockIdx.x >> 6;
    const int rt   = (blockIdx.x & 63) * 8 + (tid >> 6);
    const int m0   = rt * 32;

    const float* W = (mat == 0) ? Wq : (mat == 1) ? Wk : Wv;

    for (int i = tid; i < 2048; i += 512) {
        int n = i >> 4, kc = i & 15;
        short8 v = load_f32x8_bf16(W + n * C_DIM + kc * 8);
        Wl[((n >> 4) * 4 + (kc >> 2)) * 64 + (kc & 3) * 16 + (n & 15)] = v;
    }

    short8 afr[2][4];
#pragma unroll
    for (int ms = 0; ms < 2; ++ms) {
        const float* xrow = x + (size_t)(m0 + ms * 16 + ln15) * C_DIM + quad * 8;
#pragma unroll
        for (int ks = 0; ks < 4; ++ks)
            afr[ms][ks] = load_f32x8_bf16(xrow + ks * 32);
    }

    __syncthreads();

    const float scale = (mat == 0) ? (0.08838834764831845f * 1.4426950408889634f)
                                   : 1.0f;
    const int b  = m0 >> 12;
    const int tl = m0 & 4095;

#pragma unroll
    for (int nt = 0; nt < 8; ++nt) {
        f32x4 acc0 = {0.f, 0.f, 0.f, 0.f};
        f32x4 acc1 = {0.f, 0.f, 0.f, 0.f};
#pragma unroll
        for (int ks = 0; ks < 4; ++ks) {
            short8 bfr = Wl[(nt * 4 + ks) * 64 + lane];
            if (mat == 2) {
                acc0 = __builtin_amdgcn_mfma_f32_16x16x32_bf16(afr[0][ks], bfr, acc0, 0, 0, 0);
                acc1 = __builtin_amdgcn_mfma_f32_16x16x32_bf16(afr[1][ks], bfr, acc1, 0, 0, 0);
            } else {
                acc0 = __builtin_amdgcn_mfma_f32_16x16x32_bf16(bfr, afr[0][ks], acc0, 0, 0, 0);
                acc1 = __builtin_amdgcn_mfma_f32_16x16x32_bf16(bfr, afr[1][ks], acc1, 0, 0, 0);
            }
        }
        if (mat == 0) {
            short4v s0, s1;
#pragma unroll
            for (int r = 0; r < 4; ++r) { s0[r] = f2bf(acc0[r] * scale); s1[r] = f2bf(acc1[r] * scale); }
            *(short4v*)&Q[(size_t)(m0 + ln15) * C_DIM + nt * 16 + quad * 4]      = s0;
            *(short4v*)&Q[(size_t)(m0 + 16 + ln15) * C_DIM + nt * 16 + quad * 4] = s1;
        } else if (mat == 1) {
            const int t16 = tl >> 4;
            short4v s0, s1;
#pragma unroll
            for (int r = 0; r < 4; ++r) { s0[r] = f2bf(acc0[r]); s1[r] = f2bf(acc1[r]); }
            size_t base = (((size_t)(b * 256 + t16) * 4 + (nt >> 1)) << 9)
                        + (((nt & 1) * 2 + (quad >> 1)) * 128) + ln15 * 8 + (quad & 1) * 4;
            *(short4v*)&Kf[base]        = s0;
            *(short4v*)&Kf[base + 2048] = s1;
        } else {
            const int kvc = tl >> 5;
            short4v s0, s1;
#pragma unroll
            for (int r = 0; r < 4; ++r) { s0[r] = f2bf(acc0[r]); s1[r] = f2bf(acc1[r]); }
            short* vbase = Vf + (((size_t)(b * 128 + kvc) * 8 + nt) << 9);
            *(short4v*)&vbase[((quad >> 1) * 16 + ln15) * 8 + (quad & 1) * 4]       = s0;
            *(short4v*)&vbase[(((quad >> 1) + 2) * 16 + ln15) * 8 + (quad & 1) * 4] = s1;
        }
    }
}

// ---------------------------------------------------------------------------
// Kernel 2: causal flash attention. R14: 512 threads / 8 waves per block
// (2 waves/SIMD) on the SAME 148 KB LDS footprint and BK=128 double-buffered
// rounds. R13 was latency-bound at 1 wave/SIMD (MfmaUtil 13%, VALUBusy 20%,
// Occupancy 9.5%): every ds_read->MFMA chain, the softmax exp2 chain and
// both per-round barrier drains were fully exposed. Doubling waves/SIMD
// overlaps one wave's latency under the other's issue.
//   QK: wave w owns kv rows [w*16, w*16+16)         (was 32 rows / wave)
//   PV: wave (qg=w>>2, dg=w&3) owns qt {2qg,2qg+1} x dt {2dg,2dg+1}
//   stage: each wave DMAs a 4 KB slice of K and of V (was 8 KB each)
// Layouts, barriers/round (2), dbuf timing, masking, fixed-max exp2 softmax
// all unchanged.
// ---------------------------------------------------------------------------
__global__ __launch_bounds__(512, 2) void flash_attn(
    const short* __restrict__ Q, const short* __restrict__ Kf,
    const short* __restrict__ Vf, float* __restrict__ part,
    float* __restrict__ lpart)
{
    __shared__ short Klds[2][16384];      // 2 x 32 KB: 128 kv rows frag-ordered
    __shared__ short Vlds[2][16384];      // 2 x 32 KB
    __shared__ short Plds[64 * 132];      // 16.9 KB: P[q][kv128], stride 132
    __shared__ float lsum[64];

    const int tid  = threadIdx.x;
    const int w    = tid >> 6;            // 0..7
    const int lane = tid & 63;
    const int ln15 = lane & 15;
    const int quad = lane >> 4;
    const int qg   = w >> 2;              // PV: q-tile pair {2qg, 2qg+1}
    const int dg   = w & 3;               // PV: d-tile pair {2dg, 2dg+1}
    const int bid  = blockIdx.x;
    const int x    = bid & 7;             // XCD slot
    const int b    = x >> 1;
    const int h    = x & 1;               // 128-round parity half
    const int j    = bid >> 3;            // [0,32): pair (j, 63-j)

    const short* Qb = Q  + (size_t)b * T_SEQ * C_DIM;
    const short* Kb = Kf + ((size_t)b << 19);
    const short* Vb = Vf + ((size_t)b << 19);

    for (int half = 0; half < 2; ++half) {
        const int qc   = half ? (63 - j) : j;
        const int q0   = qc * 64;
        const int kmax = (qc * 64 + 63) >> 7;   // last 128-wide round index

        // Q B-frags for 4 q-subtiles (every wave needs all 4 for QK)
        short8 qf[4][4];
#pragma unroll
        for (int qt = 0; qt < 4; ++qt) {
            const short* qrow = Qb + (size_t)(q0 + qt * 16 + ln15) * C_DIM + quad * 8;
#pragma unroll
            for (int ks = 0; ks < 4; ++ks)
                qf[qt][ks] = *(const short8*)(qrow + ks * 32);
        }

        f32x4 acc[2][2];
#pragma unroll
        for (int qi = 0; qi < 2; ++qi)
#pragma unroll
            for (int di = 0; di < 2; ++di)
                acc[qi][di] = (f32x4){0.f, 0.f, 0.f, 0.f};
        float l_i[4] = {0.f, 0.f, 0.f, 0.f};

        // prologue: stage round h into buffer 0 (wave stages its 4 KB slices)
        if (h <= kmax) {
            const short* gk = Kb + ((size_t)h << 14) + w * 2048;   // r*16384
            const short* gv = Vb + ((size_t)h << 14) + w * 2048;
#pragma unroll
            for (int i = 0; i < 4; ++i) {
                async_cp16(gk + i * 512 + lane * 8, &Klds[0][w * 2048 + i * 512]);
                async_cp16(gv + i * 512 + lane * 8, &Vlds[0][w * 2048 + i * 512]);
            }
        }

        int idx = 0;
        for (int r = h; r <= kmax; r += 2, ++idx) {
            const int cur = idx & 1;
            const int kv0 = r << 7;

            __syncthreads();   // TOP: stage(r) drained; all prior-round reads done

            // issue stage(r+2) into the other buffer — a full round in flight
            if (r + 2 <= kmax) {
                const short* gk = Kb + ((size_t)(r + 2) << 14) + w * 2048;
                const short* gv = Vb + ((size_t)(r + 2) << 14) + w * 2048;
                short* lk = &Klds[cur ^ 1][w * 2048];
                short* lv = &Vlds[cur ^ 1][w * 2048];
#pragma unroll
                for (int i = 0; i < 4; ++i) {
                    async_cp16(gk + i * 512 + lane * 8, lk + i * 512);
                    async_cp16(gv + i * 512 + lane * 8, lv + i * 512);
                }
            }

            // ---- phase A: QK. wave w owns kv rows [w*16, w*16+16) ----
            short8 kfr[4];
#pragma unroll
            for (int ks = 0; ks < 4; ++ks)
                kfr[ks] = *(const short8*)&Klds[cur][(w * 4 + ks) * 512 + lane * 8];

            f32x4 St[4];
#pragma unroll
            for (int qt = 0; qt < 4; ++qt) {
                f32x4 s = {0.f, 0.f, 0.f, 0.f};
#pragma unroll
                for (int ks = 0; ks < 4; ++ks)
                    s = __builtin_amdgcn_mfma_f32_16x16x32_bf16(kfr[ks], qf[qt][ks], s, 0, 0, 0);
                St[qt] = s;
            }

            if (kv0 + 128 > q0) {   // chunk crosses/passes the diagonal
#pragma unroll
                for (int qt = 0; qt < 4; ++qt) {
                    int qcol = q0 + qt * 16 + ln15;
#pragma unroll
                    for (int rr = 0; rr < 4; ++rr)
                        if (kv0 + w * 16 + quad * 4 + rr > qcol)
                            St[qt][rr] = -INFINITY;
                }
            }

            // fixed-max softmax -> P (Q carries scale*log2e; exp2 domain)
#pragma unroll
            for (int qt = 0; qt < 4; ++qt) {
                float p0 = __builtin_amdgcn_exp2f(St[qt][0] - 16.f);
                float p1 = __builtin_amdgcn_exp2f(St[qt][1] - 16.f);
                float p2 = __builtin_amdgcn_exp2f(St[qt][2] - 16.f);
                float p3 = __builtin_amdgcn_exp2f(St[qt][3] - 16.f);
                l_i[qt] += (p0 + p1) + (p2 + p3);
                uint2 pk;
                pk.x = pk_bf16(p0, p1);
                pk.y = pk_bf16(p2, p3);
                *(uint2*)&Plds[(qt * 16 + ln15) * 132 + w * 16 + quad * 4] = pk;
            }

            __syncthreads();   // MID: P complete (K reads also done)

            // ---- phase B: PV. wave owns qt {2qg,2qg+1} x dt {2dg,2dg+1} ----
#pragma unroll
            for (int kc = 0; kc < 4; ++kc) {        // 4 x 32-kv chunks
                short8 vfr[2];
#pragma unroll
                for (int di = 0; di < 2; ++di)
                    vfr[di] = *(const short8*)&Vlds[cur][(kc * 8 + dg * 2 + di) * 512 + lane * 8];
#pragma unroll
                for (int qi = 0; qi < 2; ++qi) {
                    short8 pf = *(const short8*)&Plds[((qg * 2 + qi) * 16 + ln15) * 132 + kc * 32 + quad * 8];
#pragma unroll
                    for (int di = 0; di < 2; ++di)
                        acc[qi][di] = __builtin_amdgcn_mfma_f32_16x16x32_bf16(vfr[di], pf, acc[qi][di], 0, 0, 0);
                }
            }
            // loop back: TOP barrier protects P overwrite & V restage
        }

        // ---- l combine + partial store ----
        __syncthreads();
        if (tid < 64) lsum[tid] = 0.f;
        __syncthreads();
#pragma unroll
        for (int qt = 0; qt < 4; ++qt)
            atomicAdd(&lsum[qt * 16 + ln15], l_i[qt]);
        __syncthreads();

        const size_t pb = ((size_t)((h * 4 + b) * 64 + qc)) * 8192;
#pragma unroll
        for (int qi = 0; qi < 2; ++qi)
#pragma unroll
            for (int di = 0; di < 2; ++di) {
                float4 v = make_float4(acc[qi][di][0], acc[qi][di][1],
                                       acc[qi][di][2], acc[qi][di][3]);
                *(float4*)&part[pb + ((qg * 2 + qi) * 16 + ln15) * 128
                                + (dg * 2 + di) * 16 + quad * 4] = v;
            }
        if (tid < 64)
            lpart[(size_t)((h * 4 + b) * 64 + qc) * 64 + tid] = lsum[tid];
        __syncthreads();   // lsum/P safe before next half
    }
}

// ---------------------------------------------------------------------------
// Kernel 3: combine the 2 kv-halves: out = (P0 + P1) / (l0 + l1). (unchanged)
// ---------------------------------------------------------------------------
__global__ __launch_bounds__(256) void combine(
    const float* __restrict__ part, const float* __restrict__ lpart,
    float* __restrict__ out)
{
    const int tid = threadIdx.x;
    const int bid = blockIdx.x;
    const size_t PLANE  = (size_t)4 * 64 * 8192;
    const size_t LPLANE = (size_t)4 * 64 * 64;

#pragma unroll
    for (int i = 0; i < 8; ++i) {
        int f4  = bid * 2048 + i * 256 + tid;
        int c4  = f4 & 31;
        int row = f4 >> 5;
        int b   = row >> 12;
        int t   = row & 4095;
        int qc  = t >> 6;
        int qr  = t & 63;
        size_t base = (size_t)((b * 64 + qc)) * 8192 + qr * 128 + c4 * 4;
        float4 p0 = *(const float4*)&part[base];
        float4 p1 = *(const float4*)&part[base + PLANE];
        float  l  = lpart[(size_t)(b * 64 + qc) * 64 + qr]
                  + lpart[(size_t)(b * 64 + qc) * 64 + qr + LPLANE];
        float li = 1.0f / l;
        float4 v;
        v.x = (p0.x + p1.x) * li;
        v.y = (p0.y + p1.y) * li;
        v.z = (p0.z + p1.z) * li;
        v.w = (p0.w + p1.w) * li;
        ((float4*)out)[f4] = v;
    }
}

extern "C" void kernel_launch(void* const* d_in, const int* in_sizes, int n_in,
                              void* d_out, int out_size, void* d_ws, size_t ws_size,
                              hipStream_t stream) {
    const float* x  = (const float*)d_in[0];
    const float* Wq = (const float*)d_in[1];
    const float* Wk = (const float*)d_in[2];
    const float* Wv = (const float*)d_in[3];
    float* out = (float*)d_out;

    const size_t elems = (size_t)B_SZ * T_SEQ * C_DIM;   // 2,097,152
    short* Q  = (short*)d_ws;
    short* Kf = Q  + elems;
    short* Vf = Kf + elems;
    float* part  = (float*)(Vf + elems);
    float* lpart = part + (size_t)2 * 4 * 64 * 8192;

    hipLaunchKernelGGL(qkv_proj, dim3(192), dim3(512), 0, stream,
                       x, Wq, Wk, Wv, Q, Kf, Vf);
    // 256 pair-balanced blocks: (j,63-j) x 4 batches x 2 kv-halves
    hipLaunchKernelGGL(flash_attn, dim3(256), dim3(512), 0, stream,
                       Q, Kf, Vf, part, lpart);
    hipLaunchKernelGGL(combine, dim3(256), dim3(256), 0, stream,
                       part, lpart, out);
}

// Round 2
// 123.514 us; speedup vs baseline: 1.0356x; 1.0187x over previous
//
#include <hip/hip_runtime.h>
#include <hip/hip_bf16.h>
#include <math.h>

#define T_SEQ 4096
#define C_DIM 128
#define B_SZ  4

typedef __attribute__((ext_vector_type(8))) short short8;
typedef __attribute__((ext_vector_type(4))) short short4v;
typedef __attribute__((ext_vector_type(4))) float f32x4;

__device__ __forceinline__ short f2bf(float f) {
    union { float fv; unsigned u; } v; v.fv = f;
    unsigned r = v.u + 0x7fff + ((v.u >> 16) & 1);
    return (short)(r >> 16);
}

__device__ __forceinline__ unsigned pk_bf16(float a, float b) {
    union { __hip_bfloat162 h2; unsigned u; } c;
    c.h2 = __float22bfloat162_rn(make_float2(a, b));
    return c.u;
}

__device__ __forceinline__ short8 load_f32x8_bf16(const float* p) {
    const float4* q = (const float4*)p;
    float4 a = q[0], b = q[1];
    short8 r;
    r[0] = f2bf(a.x); r[1] = f2bf(a.y); r[2] = f2bf(a.z); r[3] = f2bf(a.w);
    r[4] = f2bf(b.x); r[5] = f2bf(b.y); r[6] = f2bf(b.z); r[7] = f2bf(b.w);
    return r;
}

// 16B-per-lane async global->LDS DMA (wave-uniform LDS base + lane*16).
__device__ __forceinline__ void async_cp16(const short* g, short* l) {
    __builtin_amdgcn_global_load_lds(
        (const __attribute__((address_space(1))) unsigned int*)g,
        (__attribute__((address_space(3))) unsigned int*)l, 16, 0, 0);
}

// ---------------------------------------------------------------------------
// Kernel 1: QKV projection (unchanged). Q/K via transposed-C MFMA ->
// short4 stores; K/V in fragment-ordered layouts for flash's linear DMA.
// ---------------------------------------------------------------------------
__global__ __launch_bounds__(512) void qkv_proj(
    const float* __restrict__ x, const float* __restrict__ Wq,
    const float* __restrict__ Wk, const float* __restrict__ Wv,
    short* __restrict__ Q, short* __restrict__ Kf, short* __restrict__ Vf)
{
    __shared__ short8 Wl[2048];

    const int tid  = threadIdx.x;
    const int lane = tid & 63;
    const int ln15 = lane & 15;
    const int quad = lane >> 4;
    const int mat  = blockIdx.x >> 6;
    const int rt   = (blockIdx.x & 63) * 8 + (tid >> 6);
    const int m0   = rt * 32;

    const float* W = (mat == 0) ? Wq : (mat == 1) ? Wk : Wv;

    for (int i = tid; i < 2048; i += 512) {
        int n = i >> 4, kc = i & 15;
        short8 v = load_f32x8_bf16(W + n * C_DIM + kc * 8);
        Wl[((n >> 4) * 4 + (kc >> 2)) * 64 + (kc & 3) * 16 + (n & 15)] = v;
    }

    short8 afr[2][4];
#pragma unroll
    for (int ms = 0; ms < 2; ++ms) {
        const float* xrow = x + (size_t)(m0 + ms * 16 + ln15) * C_DIM + quad * 8;
#pragma unroll
        for (int ks = 0; ks < 4; ++ks)
            afr[ms][ks] = load_f32x8_bf16(xrow + ks * 32);
    }

    __syncthreads();

    const float scale = (mat == 0) ? (0.08838834764831845f * 1.4426950408889634f)
                                   : 1.0f;
    const int b  = m0 >> 12;
    const int tl = m0 & 4095;

#pragma unroll
    for (int nt = 0; nt < 8; ++nt) {
        f32x4 acc0 = {0.f, 0.f, 0.f, 0.f};
        f32x4 acc1 = {0.f, 0.f, 0.f, 0.f};
#pragma unroll
        for (int ks = 0; ks < 4; ++ks) {
            short8 bfr = Wl[(nt * 4 + ks) * 64 + lane];
            if (mat == 2) {
                acc0 = __builtin_amdgcn_mfma_f32_16x16x32_bf16(afr[0][ks], bfr, acc0, 0, 0, 0);
                acc1 = __builtin_amdgcn_mfma_f32_16x16x32_bf16(afr[1][ks], bfr, acc1, 0, 0, 0);
            } else {
                acc0 = __builtin_amdgcn_mfma_f32_16x16x32_bf16(bfr, afr[0][ks], acc0, 0, 0, 0);
                acc1 = __builtin_amdgcn_mfma_f32_16x16x32_bf16(bfr, afr[1][ks], acc1, 0, 0, 0);
            }
        }
        if (mat == 0) {
            short4v s0, s1;
#pragma unroll
            for (int r = 0; r < 4; ++r) { s0[r] = f2bf(acc0[r] * scale); s1[r] = f2bf(acc1[r] * scale); }
            *(short4v*)&Q[(size_t)(m0 + ln15) * C_DIM + nt * 16 + quad * 4]      = s0;
            *(short4v*)&Q[(size_t)(m0 + 16 + ln15) * C_DIM + nt * 16 + quad * 4] = s1;
        } else if (mat == 1) {
            const int t16 = tl >> 4;
            short4v s0, s1;
#pragma unroll
            for (int r = 0; r < 4; ++r) { s0[r] = f2bf(acc0[r]); s1[r] = f2bf(acc1[r]); }
            size_t base = (((size_t)(b * 256 + t16) * 4 + (nt >> 1)) << 9)
                        + (((nt & 1) * 2 + (quad >> 1)) * 128) + ln15 * 8 + (quad & 1) * 4;
            *(short4v*)&Kf[base]        = s0;
            *(short4v*)&Kf[base + 2048] = s1;
        } else {
            const int kvc = tl >> 5;
            short4v s0, s1;
#pragma unroll
            for (int r = 0; r < 4; ++r) { s0[r] = f2bf(acc0[r]); s1[r] = f2bf(acc1[r]); }
            short* vbase = Vf + (((size_t)(b * 128 + kvc) * 8 + nt) << 9);
            *(short4v*)&vbase[((quad >> 1) * 16 + ln15) * 8 + (quad & 1) * 4]       = s0;
            *(short4v*)&vbase[(((quad >> 1) + 2) * 16 + ln15) * 8 + (quad & 1) * 4] = s1;
        }
    }
}

// ---------------------------------------------------------------------------
// Kernel 2: causal flash attention. R15: counted-waitcnt barriers (T4).
// R14 post-mortem: __syncthreads() at MID emitted s_waitcnt vmcnt(0), force-
// draining the stage(r+2) DMA ~400 cy after issue -> ~1k+ cy block-wide
// stall per round (why 2 waves/SIMD didn't help). Now raw s_barrier with
// selective waits: TOP = vmcnt(0) (stage(r), issued a FULL round earlier,
// near-free) ; MID = lgkmcnt(0) only (P visibility) -- DMA stays in flight
// across MID, through PV, drained at next TOP. Buffers are 4 DISTINCT
// __shared__ arrays + 2x-unrolled round loop so the compiler can prove
// ds_read(cur) does not alias DMA(other) and inserts no spurious vmcnt.
// Work split unchanged from R14 (8 waves: QK kv-rows w*16.., PV 2qt x 2dt).
// ---------------------------------------------------------------------------

#define ROUND_BODY(KC, VC, KN, VN, R)                                        \
  {                                                                          \
    const int kv0 = (R) << 7;                                                \
    /* TOP: stage(R) done (issued a full round ago); all prior reads done */ \
    asm volatile("s_waitcnt vmcnt(0)" ::: "memory");                         \
    __builtin_amdgcn_sched_barrier(0);                                       \
    __builtin_amdgcn_s_barrier();                                            \
    __builtin_amdgcn_sched_barrier(0);                                       \
    if ((R) + 2 <= kmax) {                                                   \
      const short* gk = Kb + ((size_t)((R) + 2) << 14) + w * 2048;           \
      const short* gv = Vb + ((size_t)((R) + 2) << 14) + w * 2048;           \
      _Pragma("unroll")                                                      \
      for (int i = 0; i < 4; ++i) {                                          \
        async_cp16(gk + i * 512 + lane * 8, &KN[w * 2048 + i * 512]);        \
        async_cp16(gv + i * 512 + lane * 8, &VN[w * 2048 + i * 512]);        \
      }                                                                      \
    }                                                                        \
    /* ---- phase A: QK. wave w owns kv rows [w*16, w*16+16) ---- */         \
    short8 kfr[4];                                                           \
    _Pragma("unroll")                                                        \
    for (int ks = 0; ks < 4; ++ks)                                           \
      kfr[ks] = *(const short8*)&KC[(w * 4 + ks) * 512 + lane * 8];          \
    f32x4 St[4];                                                             \
    _Pragma("unroll")                                                        \
    for (int qt = 0; qt < 4; ++qt) {                                         \
      f32x4 s = {0.f, 0.f, 0.f, 0.f};                                        \
      _Pragma("unroll")                                                      \
      for (int ks = 0; ks < 4; ++ks)                                         \
        s = __builtin_amdgcn_mfma_f32_16x16x32_bf16(kfr[ks], qf[qt][ks], s,  \
                                                    0, 0, 0);                \
      St[qt] = s;                                                            \
    }                                                                        \
    if (kv0 + 128 > q0) {                                                    \
      _Pragma("unroll")                                                      \
      for (int qt = 0; qt < 4; ++qt) {                                       \
        int qcol = q0 + qt * 16 + ln15;                                      \
        _Pragma("unroll")                                                    \
        for (int rr = 0; rr < 4; ++rr)                                       \
          if (kv0 + w * 16 + quad * 4 + rr > qcol) St[qt][rr] = -INFINITY;   \
      }                                                                      \
    }                                                                        \
    _Pragma("unroll")                                                        \
    for (int qt = 0; qt < 4; ++qt) {                                         \
      float p0 = __builtin_amdgcn_exp2f(St[qt][0] - 16.f);                   \
      float p1 = __builtin_amdgcn_exp2f(St[qt][1] - 16.f);                   \
      float p2 = __builtin_amdgcn_exp2f(St[qt][2] - 16.f);                   \
      float p3 = __builtin_amdgcn_exp2f(St[qt][3] - 16.f);                   \
      l_i[qt] += (p0 + p1) + (p2 + p3);                                      \
      uint2 pk;                                                              \
      pk.x = pk_bf16(p0, p1);                                                \
      pk.y = pk_bf16(p2, p3);                                                \
      *(uint2*)&Plds[(qt * 16 + ln15) * 132 + w * 16 + quad * 4] = pk;       \
    }                                                                        \
    /* MID: P visible to all; DMA stays in flight (no vmcnt drain) */        \
    asm volatile("s_waitcnt lgkmcnt(0)" ::: "memory");                       \
    __builtin_amdgcn_sched_barrier(0);                                       \
    __builtin_amdgcn_s_barrier();                                            \
    __builtin_amdgcn_sched_barrier(0);                                       \
    /* ---- phase B: PV. wave owns qt {2qg,2qg+1} x dt {2dg,2dg+1} ---- */   \
    _Pragma("unroll")                                                        \
    for (int kc = 0; kc < 4; ++kc) {                                         \
      short8 vfr[2];                                                         \
      _Pragma("unroll")                                                      \
      for (int di = 0; di < 2; ++di)                                         \
        vfr[di] =                                                            \
            *(const short8*)&VC[(kc * 8 + dg * 2 + di) * 512 + lane * 8];    \
      _Pragma("unroll")                                                      \
      for (int qi = 0; qi < 2; ++qi) {                                       \
        short8 pf = *(const short8*)&Plds[((qg * 2 + qi) * 16 + ln15) * 132  \
                                          + kc * 32 + quad * 8];             \
        _Pragma("unroll")                                                    \
        for (int di = 0; di < 2; ++di)                                       \
          acc[qi][di] = __builtin_amdgcn_mfma_f32_16x16x32_bf16(             \
              vfr[di], pf, acc[qi][di], 0, 0, 0);                            \
      }                                                                      \
    }                                                                        \
  }

__global__ __launch_bounds__(512, 2) void flash_attn(
    const short* __restrict__ Q, const short* __restrict__ Kf,
    const short* __restrict__ Vf, float* __restrict__ part,
    float* __restrict__ lpart)
{
    __shared__ short Klds0[16384];        // 32 KB: 128 kv rows frag-ordered
    __shared__ short Klds1[16384];        // 32 KB (distinct object: alias-free)
    __shared__ short Vlds0[16384];        // 32 KB
    __shared__ short Vlds1[16384];        // 32 KB
    __shared__ short Plds[64 * 132];      // 16.9 KB: P[q][kv128], stride 132
    __shared__ float lsum[64];

    const int tid  = threadIdx.x;
    const int w    = tid >> 6;            // 0..7
    const int lane = tid & 63;
    const int ln15 = lane & 15;
    const int quad = lane >> 4;
    const int qg   = w >> 2;              // PV: q-tile pair {2qg, 2qg+1}
    const int dg   = w & 3;               // PV: d-tile pair {2dg, 2dg+1}
    const int bid  = blockIdx.x;
    const int x    = bid & 7;             // XCD slot
    const int b    = x >> 1;
    const int h    = x & 1;               // 128-round parity half
    const int j    = bid >> 3;            // [0,32): pair (j, 63-j)

    const short* Qb = Q  + (size_t)b * T_SEQ * C_DIM;
    const short* Kb = Kf + ((size_t)b << 19);
    const short* Vb = Vf + ((size_t)b << 19);

    for (int half = 0; half < 2; ++half) {
        const int qc   = half ? (63 - j) : j;
        const int q0   = qc * 64;
        const int kmax = (qc * 64 + 63) >> 7;   // last 128-wide round index

        // Q B-frags for 4 q-subtiles (every wave needs all 4 for QK)
        short8 qf[4][4];
#pragma unroll
        for (int qt = 0; qt < 4; ++qt) {
            const short* qrow = Qb + (size_t)(q0 + qt * 16 + ln15) * C_DIM + quad * 8;
#pragma unroll
            for (int ks = 0; ks < 4; ++ks)
                qf[qt][ks] = *(const short8*)(qrow + ks * 32);
        }

        f32x4 acc[2][2];
#pragma unroll
        for (int qi = 0; qi < 2; ++qi)
#pragma unroll
            for (int di = 0; di < 2; ++di)
                acc[qi][di] = (f32x4){0.f, 0.f, 0.f, 0.f};
        float l_i[4] = {0.f, 0.f, 0.f, 0.f};

        // prologue: stage round h into buffer 0 (wave stages its 4 KB slices)
        if (h <= kmax) {
            const short* gk = Kb + ((size_t)h << 14) + w * 2048;   // r*16384
            const short* gv = Vb + ((size_t)h << 14) + w * 2048;
#pragma unroll
            for (int i = 0; i < 4; ++i) {
                async_cp16(gk + i * 512 + lane * 8, &Klds0[w * 2048 + i * 512]);
                async_cp16(gv + i * 512 + lane * 8, &Vlds0[w * 2048 + i * 512]);
            }
        }

        int r = h;
        while (r <= kmax) {
            ROUND_BODY(Klds0, Vlds0, Klds1, Vlds1, r);
            r += 2;
            if (r > kmax) break;
            ROUND_BODY(Klds1, Vlds1, Klds0, Vlds0, r);
            r += 2;
        }

        // ---- l combine + partial store ----
        __syncthreads();
        if (tid < 64) lsum[tid] = 0.f;
        __syncthreads();
#pragma unroll
        for (int qt = 0; qt < 4; ++qt)
            atomicAdd(&lsum[qt * 16 + ln15], l_i[qt]);
        __syncthreads();

        const size_t pb = ((size_t)((h * 4 + b) * 64 + qc)) * 8192;
#pragma unroll
        for (int qi = 0; qi < 2; ++qi)
#pragma unroll
            for (int di = 0; di < 2; ++di) {
                float4 v = make_float4(acc[qi][di][0], acc[qi][di][1],
                                       acc[qi][di][2], acc[qi][di][3]);
                *(float4*)&part[pb + ((qg * 2 + qi) * 16 + ln15) * 128
                                + (dg * 2 + di) * 16 + quad * 4] = v;
            }
        if (tid < 64)
            lpart[(size_t)((h * 4 + b) * 64 + qc) * 64 + tid] = lsum[tid];
        __syncthreads();   // lsum/P safe before next half
    }
}

// ---------------------------------------------------------------------------
// Kernel 3: combine the 2 kv-halves: out = (P0 + P1) / (l0 + l1). (unchanged)
// ---------------------------------------------------------------------------
__global__ __launch_bounds__(256) void combine(
    const float* __restrict__ part, const float* __restrict__ lpart,
    float* __restrict__ out)
{
    const int tid = threadIdx.x;
    const int bid = blockIdx.x;
    const size_t PLANE  = (size_t)4 * 64 * 8192;
    const size_t LPLANE = (size_t)4 * 64 * 64;

#pragma unroll
    for (int i = 0; i < 8; ++i) {
        int f4  = bid * 2048 + i * 256 + tid;
        int c4  = f4 & 31;
        int row = f4 >> 5;
        int b   = row >> 12;
        int t   = row & 4095;
        int qc  = t >> 6;
        int qr  = t & 63;
        size_t base = (size_t)((b * 64 + qc)) * 8192 + qr * 128 + c4 * 4;
        float4 p0 = *(const float4*)&part[base];
        float4 p1 = *(const float4*)&part[base + PLANE];
        float  l  = lpart[(size_t)(b * 64 + qc) * 64 + qr]
                  + lpart[(size_t)(b * 64 + qc) * 64 + qr + LPLANE];
        float li = 1.0f / l;
        float4 v;
        v.x = (p0.x + p1.x) * li;
        v.y = (p0.y + p1.y) * li;
        v.z = (p0.z + p1.z) * li;
        v.w = (p0.w + p1.w) * li;
        ((float4*)out)[f4] = v;
    }
}

extern "C" void kernel_launch(void* const* d_in, const int* in_sizes, int n_in,
                              void* d_out, int out_size, void* d_ws, size_t ws_size,
                              hipStream_t stream) {
    const float* x  = (const float*)d_in[0];
    const float* Wq = (const float*)d_in[1];
    const float* Wk = (const float*)d_in[2];
    const float* Wv = (const float*)d_in[3];
    float* out = (float*)d_out;

    const size_t elems = (size_t)B_SZ * T_SEQ * C_DIM;   // 2,097,152
    short* Q  = (short*)d_ws;
    short* Kf = Q  + elems;
    short* Vf = Kf + elems;
    float* part  = (float*)(Vf + elems);
    float* lpart = part + (size_t)2 * 4 * 64 * 8192;

    hipLaunchKernelGGL(qkv_proj, dim3(192), dim3(512), 0, stream,
                       x, Wq, Wk, Wv, Q, Kf, Vf);
    // 256 pair-balanced blocks: (j,63-j) x 4 batches x 2 kv-halves
    hipLaunchKernelGGL(flash_attn, dim3(256), dim3(512), 0, stream,
                       Q, Kf, Vf, part, lpart);
    hipLaunchKernelGGL(combine, dim3(256), dim3(256), 0, stream,
                       part, lpart, out);
}

// Round 3
// 121.536 us; speedup vs baseline: 1.0524x; 1.0163x over previous
//
#include <hip/hip_runtime.h>
#include <hip/hip_bf16.h>
#include <math.h>

#define T_SEQ 4096
#define C_DIM 128
#define B_SZ  4

typedef __attribute__((ext_vector_type(8))) short short8;
typedef __attribute__((ext_vector_type(4))) short short4v;
typedef __attribute__((ext_vector_type(4))) float f32x4;

__device__ __forceinline__ short f2bf(float f) {
    union { float fv; unsigned u; } v; v.fv = f;
    unsigned r = v.u + 0x7fff + ((v.u >> 16) & 1);
    return (short)(r >> 16);
}

__device__ __forceinline__ unsigned pk_bf16(float a, float b) {
    union { __hip_bfloat162 h2; unsigned u; } c;
    c.h2 = __float22bfloat162_rn(make_float2(a, b));
    return c.u;
}

__device__ __forceinline__ short8 load_f32x8_bf16(const float* p) {
    const float4* q = (const float4*)p;
    float4 a = q[0], b = q[1];
    short8 r;
    r[0] = f2bf(a.x); r[1] = f2bf(a.y); r[2] = f2bf(a.z); r[3] = f2bf(a.w);
    r[4] = f2bf(b.x); r[5] = f2bf(b.y); r[6] = f2bf(b.z); r[7] = f2bf(b.w);
    return r;
}

// 16B-per-lane async global->LDS DMA (wave-uniform LDS base + lane*16).
__device__ __forceinline__ void async_cp16(const short* g, short* l) {
    __builtin_amdgcn_global_load_lds(
        (const __attribute__((address_space(1))) unsigned int*)g,
        (__attribute__((address_space(3))) unsigned int*)l, 16, 0, 0);
}

// ---------------------------------------------------------------------------
// Kernel 1: QKV projection (unchanged). Q/K via transposed-C MFMA ->
// short4 stores; K/V in fragment-ordered layouts for flash's linear DMA.
// ---------------------------------------------------------------------------
__global__ __launch_bounds__(512) void qkv_proj(
    const float* __restrict__ x, const float* __restrict__ Wq,
    const float* __restrict__ Wk, const float* __restrict__ Wv,
    short* __restrict__ Q, short* __restrict__ Kf, short* __restrict__ Vf)
{
    __shared__ short8 Wl[2048];

    const int tid  = threadIdx.x;
    const int lane = tid & 63;
    const int ln15 = lane & 15;
    const int quad = lane >> 4;
    const int mat  = blockIdx.x >> 6;
    const int rt   = (blockIdx.x & 63) * 8 + (tid >> 6);
    const int m0   = rt * 32;

    const float* W = (mat == 0) ? Wq : (mat == 1) ? Wk : Wv;

    for (int i = tid; i < 2048; i += 512) {
        int n = i >> 4, kc = i & 15;
        short8 v = load_f32x8_bf16(W + n * C_DIM + kc * 8);
        Wl[((n >> 4) * 4 + (kc >> 2)) * 64 + (kc & 3) * 16 + (n & 15)] = v;
    }

    short8 afr[2][4];
#pragma unroll
    for (int ms = 0; ms < 2; ++ms) {
        const float* xrow = x + (size_t)(m0 + ms * 16 + ln15) * C_DIM + quad * 8;
#pragma unroll
        for (int ks = 0; ks < 4; ++ks)
            afr[ms][ks] = load_f32x8_bf16(xrow + ks * 32);
    }

    __syncthreads();

    const float scale = (mat == 0) ? (0.08838834764831845f * 1.4426950408889634f)
                                   : 1.0f;
    const int b  = m0 >> 12;
    const int tl = m0 & 4095;

#pragma unroll
    for (int nt = 0; nt < 8; ++nt) {
        f32x4 acc0 = {0.f, 0.f, 0.f, 0.f};
        f32x4 acc1 = {0.f, 0.f, 0.f, 0.f};
#pragma unroll
        for (int ks = 0; ks < 4; ++ks) {
            short8 bfr = Wl[(nt * 4 + ks) * 64 + lane];
            if (mat == 2) {
                acc0 = __builtin_amdgcn_mfma_f32_16x16x32_bf16(afr[0][ks], bfr, acc0, 0, 0, 0);
                acc1 = __builtin_amdgcn_mfma_f32_16x16x32_bf16(afr[1][ks], bfr, acc1, 0, 0, 0);
            } else {
                acc0 = __builtin_amdgcn_mfma_f32_16x16x32_bf16(bfr, afr[0][ks], acc0, 0, 0, 0);
                acc1 = __builtin_amdgcn_mfma_f32_16x16x32_bf16(bfr, afr[1][ks], acc1, 0, 0, 0);
            }
        }
        if (mat == 0) {
            short4v s0, s1;
#pragma unroll
            for (int r = 0; r < 4; ++r) { s0[r] = f2bf(acc0[r] * scale); s1[r] = f2bf(acc1[r] * scale); }
            *(short4v*)&Q[(size_t)(m0 + ln15) * C_DIM + nt * 16 + quad * 4]      = s0;
            *(short4v*)&Q[(size_t)(m0 + 16 + ln15) * C_DIM + nt * 16 + quad * 4] = s1;
        } else if (mat == 1) {
            const int t16 = tl >> 4;
            short4v s0, s1;
#pragma unroll
            for (int r = 0; r < 4; ++r) { s0[r] = f2bf(acc0[r]); s1[r] = f2bf(acc1[r]); }
            size_t base = (((size_t)(b * 256 + t16) * 4 + (nt >> 1)) << 9)
                        + (((nt & 1) * 2 + (quad >> 1)) * 128) + ln15 * 8 + (quad & 1) * 4;
            *(short4v*)&Kf[base]        = s0;
            *(short4v*)&Kf[base + 2048] = s1;
        } else {
            const int kvc = tl >> 5;
            short4v s0, s1;
#pragma unroll
            for (int r = 0; r < 4; ++r) { s0[r] = f2bf(acc0[r]); s1[r] = f2bf(acc1[r]); }
            short* vbase = Vf + (((size_t)(b * 128 + kvc) * 8 + nt) << 9);
            *(short4v*)&vbase[((quad >> 1) * 16 + ln15) * 8 + (quad & 1) * 4]       = s0;
            *(short4v*)&vbase[(((quad >> 1) + 2) * 16 + ln15) * 8 + (quad & 1) * 4] = s1;
        }
    }
}

// ---------------------------------------------------------------------------
// Kernel 2: causal flash attention. R16: 2 BLOCKS PER CU.
// R14 (2 waves/SIMD) and R15 (counted-waitcnt barriers) were both ~neutral:
// the round cost is a lockstep dependency chain shared by all waves of the
// single resident block -- nothing foreign fills the stalls. Fix: shrink to
// QBLK=32 q-rows, BK=64 kv-rows/round -> LDS 68.4 KB -> 2 independent
// blocks/CU (512 blocks x 256 thr, __launch_bounds__(256,2)). Block A's
// barrier/latency bubbles are filled by block B's issue. Pair balance moves
// to 32-row chunks (j,127-j); kv-parity split stays 2-way, so part/lpart/
// combine/qkv layouts are unchanged (a 64-row K/V chunk is contiguous 16 KB
// in the existing fragment ordering). R15's counted barrier waits retained.
//   QK: wave w owns kv-tile kt=w (16 rows), both qt     (8 MFMA)
//   PV: wave w owns d-tiles {2w,2w+1}, both qt, 2 kc    (8 MFMA)
//   stage: wave w DMAs 4 KB of K and of V (8 x cp16)
// ---------------------------------------------------------------------------

#define ROUND_BODY(KC, VC, KN, VN, R)                                        \
  {                                                                          \
    const int kv0 = (R) << 6;                                                \
    /* TOP: stage(R) done (issued a full round ago); all prior reads done */ \
    asm volatile("s_waitcnt vmcnt(0)" ::: "memory");                         \
    __builtin_amdgcn_sched_barrier(0);                                       \
    __builtin_amdgcn_s_barrier();                                            \
    __builtin_amdgcn_sched_barrier(0);                                       \
    if ((R) + 2 <= kmax) {                                                   \
      const short* gk = Kb + ((size_t)((R) + 2) << 13) + w * 2048;           \
      const short* gv = Vb + ((size_t)((R) + 2) << 13) + w * 2048;           \
      _Pragma("unroll")                                                      \
      for (int i = 0; i < 4; ++i) {                                          \
        async_cp16(gk + i * 512 + lane * 8, &KN[w * 2048 + i * 512]);        \
        async_cp16(gv + i * 512 + lane * 8, &VN[w * 2048 + i * 512]);        \
      }                                                                      \
    }                                                                        \
    /* ---- phase A: QK. wave w owns kv rows [w*16, w*16+16) ---- */         \
    short8 kfr[4];                                                           \
    _Pragma("unroll")                                                        \
    for (int ks = 0; ks < 4; ++ks)                                           \
      kfr[ks] = *(const short8*)&KC[(w * 4 + ks) * 512 + lane * 8];          \
    f32x4 St[2];                                                             \
    _Pragma("unroll")                                                        \
    for (int qt = 0; qt < 2; ++qt) {                                         \
      f32x4 s = {0.f, 0.f, 0.f, 0.f};                                        \
      _Pragma("unroll")                                                      \
      for (int ks = 0; ks < 4; ++ks)                                         \
        s = __builtin_amdgcn_mfma_f32_16x16x32_bf16(kfr[ks], qf[qt][ks], s,  \
                                                    0, 0, 0);                \
      St[qt] = s;                                                            \
    }                                                                        \
    if (kv0 + 64 > q0) {                                                     \
      _Pragma("unroll")                                                      \
      for (int qt = 0; qt < 2; ++qt) {                                       \
        int qcol = q0 + qt * 16 + ln15;                                      \
        _Pragma("unroll")                                                    \
        for (int rr = 0; rr < 4; ++rr)                                       \
          if (kv0 + w * 16 + quad * 4 + rr > qcol) St[qt][rr] = -INFINITY;   \
      }                                                                      \
    }                                                                        \
    _Pragma("unroll")                                                        \
    for (int qt = 0; qt < 2; ++qt) {                                         \
      float p0 = __builtin_amdgcn_exp2f(St[qt][0] - 16.f);                   \
      float p1 = __builtin_amdgcn_exp2f(St[qt][1] - 16.f);                   \
      float p2 = __builtin_amdgcn_exp2f(St[qt][2] - 16.f);                   \
      float p3 = __builtin_amdgcn_exp2f(St[qt][3] - 16.f);                   \
      l_i[qt] += (p0 + p1) + (p2 + p3);                                      \
      uint2 pk;                                                              \
      pk.x = pk_bf16(p0, p1);                                                \
      pk.y = pk_bf16(p2, p3);                                                \
      *(uint2*)&Plds[(qt * 16 + ln15) * 68 + w * 16 + quad * 4] = pk;        \
    }                                                                        \
    /* MID: P visible to all; DMA stays in flight (no vmcnt drain) */        \
    asm volatile("s_waitcnt lgkmcnt(0)" ::: "memory");                       \
    __builtin_amdgcn_sched_barrier(0);                                       \
    __builtin_amdgcn_s_barrier();                                            \
    __builtin_amdgcn_sched_barrier(0);                                       \
    /* ---- phase B: PV. wave w owns d-tiles {2w,2w+1}, both qt ---- */      \
    _Pragma("unroll")                                                        \
    for (int kc = 0; kc < 2; ++kc) {                                         \
      short8 vfr[2];                                                         \
      _Pragma("unroll")                                                      \
      for (int di = 0; di < 2; ++di)                                         \
        vfr[di] =                                                            \
            *(const short8*)&VC[(kc * 8 + w * 2 + di) * 512 + lane * 8];     \
      _Pragma("unroll")                                                      \
      for (int qi = 0; qi < 2; ++qi) {                                       \
        short8 pf = *(const short8*)&Plds[(qi * 16 + ln15) * 68              \
                                          + kc * 32 + quad * 8];             \
        _Pragma("unroll")                                                    \
        for (int di = 0; di < 2; ++di)                                       \
          acc[qi][di] = __builtin_amdgcn_mfma_f32_16x16x32_bf16(             \
              vfr[di], pf, acc[qi][di], 0, 0, 0);                            \
      }                                                                      \
    }                                                                        \
  }

__global__ __launch_bounds__(256, 2) void flash_attn(
    const short* __restrict__ Q, const short* __restrict__ Kf,
    const short* __restrict__ Vf, float* __restrict__ part,
    float* __restrict__ lpart)
{
    __shared__ short Klds0[8192];         // 16 KB: 64 kv rows frag-ordered
    __shared__ short Klds1[8192];         // 16 KB (distinct object: alias-free)
    __shared__ short Vlds0[8192];         // 16 KB
    __shared__ short Vlds1[8192];         // 16 KB
    __shared__ short Plds[32 * 68];       // 4.3 KB: P[q32][kv64], stride 68
    __shared__ float lsum[32];

    const int tid  = threadIdx.x;
    const int w    = tid >> 6;            // 0..3
    const int lane = tid & 63;
    const int ln15 = lane & 15;
    const int quad = lane >> 4;
    const int bid  = blockIdx.x;
    const int x    = bid & 7;             // XCD slot
    const int b    = x >> 1;
    const int h    = x & 1;               // 64-round parity half
    const int j    = bid >> 3;            // [0,64): pair (j, 127-j)

    const short* Qb = Q  + (size_t)b * T_SEQ * C_DIM;
    const short* Kb = Kf + ((size_t)b << 19);
    const short* Vb = Vf + ((size_t)b << 19);

    for (int half = 0; half < 2; ++half) {
        const int qc   = half ? (127 - j) : j;    // 32-row q-chunk index
        const int q0   = qc * 32;
        const int kmax = (q0 + 31) >> 6;          // last 64-wide round index

        // Q B-frags for 2 q-subtiles (every wave needs both for QK)
        short8 qf[2][4];
#pragma unroll
        for (int qt = 0; qt < 2; ++qt) {
            const short* qrow = Qb + (size_t)(q0 + qt * 16 + ln15) * C_DIM + quad * 8;
#pragma unroll
            for (int ks = 0; ks < 4; ++ks)
                qf[qt][ks] = *(const short8*)(qrow + ks * 32);
        }

        f32x4 acc[2][2];
#pragma unroll
        for (int qi = 0; qi < 2; ++qi)
#pragma unroll
            for (int di = 0; di < 2; ++di)
                acc[qi][di] = (f32x4){0.f, 0.f, 0.f, 0.f};
        float l_i[2] = {0.f, 0.f};

        // prologue: stage round h into buffer 0 (wave stages its 2+2 KB)
        if (h <= kmax) {
            const short* gk = Kb + ((size_t)h << 13) + w * 2048;
            const short* gv = Vb + ((size_t)h << 13) + w * 2048;
#pragma unroll
            for (int i = 0; i < 4; ++i) {
                async_cp16(gk + i * 512 + lane * 8, &Klds0[w * 2048 + i * 512]);
                async_cp16(gv + i * 512 + lane * 8, &Vlds0[w * 2048 + i * 512]);
            }
        }

        int r = h;
        while (r <= kmax) {
            ROUND_BODY(Klds0, Vlds0, Klds1, Vlds1, r);
            r += 2;
            if (r > kmax) break;
            ROUND_BODY(Klds1, Vlds1, Klds0, Vlds0, r);
            r += 2;
        }

        // ---- l combine + partial store ----
        __syncthreads();
        if (tid < 32) lsum[tid] = 0.f;
        __syncthreads();
#pragma unroll
        for (int qt = 0; qt < 2; ++qt)
            atomicAdd(&lsum[qt * 16 + ln15], l_i[qt]);
        __syncthreads();

        const size_t pb = (size_t)(h * 4 + b) * 524288 + (size_t)q0 * 128;
#pragma unroll
        for (int qi = 0; qi < 2; ++qi)
#pragma unroll
            for (int di = 0; di < 2; ++di) {
                float4 v = make_float4(acc[qi][di][0], acc[qi][di][1],
                                       acc[qi][di][2], acc[qi][di][3]);
                *(float4*)&part[pb + (qi * 16 + ln15) * 128
                                + (w * 2 + di) * 16 + quad * 4] = v;
            }
        if (tid < 32)
            lpart[(size_t)(h * 4 + b) * 4096 + q0 + tid] = lsum[tid];
        __syncthreads();   // lsum/P safe before next half
    }
}

// ---------------------------------------------------------------------------
// Kernel 3: combine the 2 kv-halves: out = (P0 + P1) / (l0 + l1). (unchanged)
// ---------------------------------------------------------------------------
__global__ __launch_bounds__(256) void combine(
    const float* __restrict__ part, const float* __restrict__ lpart,
    float* __restrict__ out)
{
    const int tid = threadIdx.x;
    const int bid = blockIdx.x;
    const size_t PLANE  = (size_t)4 * 64 * 8192;
    const size_t LPLANE = (size_t)4 * 64 * 64;

#pragma unroll
    for (int i = 0; i < 8; ++i) {
        int f4  = bid * 2048 + i * 256 + tid;
        int c4  = f4 & 31;
        int row = f4 >> 5;
        int b   = row >> 12;
        int t   = row & 4095;
        int qc  = t >> 6;
        int qr  = t & 63;
        size_t base = (size_t)((b * 64 + qc)) * 8192 + qr * 128 + c4 * 4;
        float4 p0 = *(const float4*)&part[base];
        float4 p1 = *(const float4*)&part[base + PLANE];
        float  l  = lpart[(size_t)(b * 64 + qc) * 64 + qr]
                  + lpart[(size_t)(b * 64 + qc) * 64 + qr + LPLANE];
        float li = 1.0f / l;
        float4 v;
        v.x = (p0.x + p1.x) * li;
        v.y = (p0.y + p1.y) * li;
        v.z = (p0.z + p1.z) * li;
        v.w = (p0.w + p1.w) * li;
        ((float4*)out)[f4] = v;
    }
}

extern "C" void kernel_launch(void* const* d_in, const int* in_sizes, int n_in,
                              void* d_out, int out_size, void* d_ws, size_t ws_size,
                              hipStream_t stream) {
    const float* x  = (const float*)d_in[0];
    const float* Wq = (const float*)d_in[1];
    const float* Wk = (const float*)d_in[2];
    const float* Wv = (const float*)d_in[3];
    float* out = (float*)d_out;

    const size_t elems = (size_t)B_SZ * T_SEQ * C_DIM;   // 2,097,152
    short* Q  = (short*)d_ws;
    short* Kf = Q  + elems;
    short* Vf = Kf + elems;
    float* part  = (float*)(Vf + elems);
    float* lpart = part + (size_t)2 * 4 * 64 * 8192;

    hipLaunchKernelGGL(qkv_proj, dim3(192), dim3(512), 0, stream,
                       x, Wq, Wk, Wv, Q, Kf, Vf);
    // 512 pair-balanced blocks: (j,127-j) x 4 batches x 2 kv-halves
    hipLaunchKernelGGL(flash_attn, dim3(512), dim3(256), 0, stream,
                       Q, Kf, Vf, part, lpart);
    hipLaunchKernelGGL(combine, dim3(256), dim3(256), 0, stream,
                       part, lpart, out);
}